// Round 13
// baseline (4698.243 us; speedup 1.0000x reference)
//
#include <hip/hip_runtime.h>
#include <math.h>

#define B_SZ 32
#define T_SZ 2048
#define DIN 256
#define DH 256
#define FOUR_D 1024

// scan decomposition: 8 WGs per batch, 512 threads each (R9-proven skeleton)
#define NW 8
#define DPW 32
#define COLS 128       // preact cols per WG (4 gates x 32 dims)
#define KSEG 4         // 512 threads = 128 cols x 4 K-segments
#define KLEN 64        // K elements per segment -> 8 bf16 chunks of 8

__global__ void zero_ws(unsigned int* p, int n) {
    int i = blockIdx.x * blockDim.x + threadIdx.x;
    if (i < n) p[i] = 0u;
}

// px[r][f] = bias[f] + sum_k x_row(r)[k] * W[k][f];  r = tt*32 + b   (proven)
__global__ __launch_bounds__(256) void px_gemm(
    const float* __restrict__ x, const float* __restrict__ W,
    const float* __restrict__ bias, float* __restrict__ px,
    int t0)
{
    __shared__ float xt[16][DIN];
    const int tid = threadIdx.x;
    const int rbase = blockIdx.x * 16;

    {
        int row = tid >> 4;
        int seg = (tid & 15) * 16;
        int r = rbase + row;
        int bb = r & 31;
        int tt = r >> 5;
        const float4* s4 = (const float4*)(x + ((size_t)bb * T_SZ + (size_t)(t0 + tt)) * DIN + seg);
        float4* dst = (float4*)&xt[row][seg];
        dst[0] = s4[0]; dst[1] = s4[1]; dst[2] = s4[2]; dst[3] = s4[3];
    }
    __syncthreads();

    const int j = tid * 4;
    float4 bv = *(const float4*)&bias[j];
    float acc[16][4];
#pragma unroll
    for (int r = 0; r < 16; ++r) {
        acc[r][0] = bv.x; acc[r][1] = bv.y; acc[r][2] = bv.z; acc[r][3] = bv.w;
    }

    for (int k = 0; k < DIN; k += 4) {
        float4 w0 = *(const float4*)&W[(size_t)(k + 0) * FOUR_D + j];
        float4 w1 = *(const float4*)&W[(size_t)(k + 1) * FOUR_D + j];
        float4 w2 = *(const float4*)&W[(size_t)(k + 2) * FOUR_D + j];
        float4 w3 = *(const float4*)&W[(size_t)(k + 3) * FOUR_D + j];
#pragma unroll
        for (int r = 0; r < 16; ++r) {
            float4 xv = *(const float4*)&xt[r][k];
            acc[r][0] += xv.x * w0.x + xv.y * w1.x + xv.z * w2.x + xv.w * w3.x;
            acc[r][1] += xv.x * w0.y + xv.y * w1.y + xv.z * w2.y + xv.w * w3.y;
            acc[r][2] += xv.x * w0.z + xv.y * w1.z + xv.z * w2.z + xv.w * w3.z;
            acc[r][3] += xv.x * w0.w + xv.y * w1.w + xv.z * w2.w + xv.w * w3.w;
        }
    }

#pragma unroll
    for (int r = 0; r < 16; ++r) {
        float4 st = make_float4(acc[r][0], acc[r][1], acc[r][2], acc[r][3]);
        *(float4*)&px[((size_t)(rbase + r)) * FOUR_D + j] = st;
    }
}

__device__ __forceinline__ float bfu(unsigned u) { return __uint_as_float(u); }

// Transposed scan (R9 skeleton) with the WG's U-slice resident in LDS as
// bf16 (64 KB, loaded+rounded once at prologue). The compiler cannot remat
// LDS, so the per-step 128 KB L2 re-stream (R6-R12's hidden cost) is gone.
// Layout: u_lds[c][k] bf16, with the 16B chunk index XOR-swizzled by (c&7)
// so a wave's 64 lanes hit all 8 bank-quads (exact 8-access/bank minimum).
// h stays fp32; accumulation fp32. Poll: proven agent-scope 64-bit tagged
// atomics, parity double-buffered.
__global__ __launch_bounds__(512, 2) void lstm_scan11(
    const float* __restrict__ px, const float* __restrict__ U,
    float* __restrict__ out, unsigned long long* __restrict__ hbuf,
    float* __restrict__ cstate, int t0, int ct)
{
    __shared__ unsigned short u_lds[COLS][256];   // 64 KB bf16 U-slice
    __shared__ float h_lds[DH];
    __shared__ float red[KSEG][COLS + 1];
    __shared__ float act_s[COLS];

    const int b = blockIdx.x >> 3;     // batch (batch-contiguous)
    const int w = blockIdx.x & 7;      // WG-within-batch
    const int tid = threadIdx.x;
    const int c = tid & (COLS - 1);    // col within WG: 0..127
    const int seg = tid >> 7;          // 0..3
    const int kbase = seg << 6;        // 0,64,128,192
    const int cx = c & 7;              // swizzle key
    const int gg = c >> 5, jj = c & 31;
    const int colg = (gg << 8) + (w << 5) + jj;   // global preact column

    // ---- prologue: stage U-slice to LDS as bf16 (RNE), chunk-swizzled.
    // lin = it*512+tid: k = lin>>7, cidx = lin&127 -> 32 consecutive global
    // cols per 32 lanes (coalesced).
#pragma unroll 4
    for (int it = 0; it < 64; ++it) {
        int lin = (it << 9) + tid;
        int k = lin >> 7;
        int cidx = lin & 127;
        int gcol = ((cidx >> 5) << 8) + (w << 5) + (cidx & 31);
        float v = U[(size_t)k * FOUR_D + gcol];
        unsigned ub = __float_as_uint(v);
        unsigned r = (ub + 0x7fffu + ((ub >> 16) & 1u)) >> 16;   // RNE -> bf16
        int m = k >> 3, j = k & 7;                                // chunk, elem
        u_lds[cidx][((m ^ (cidx & 7)) << 3) + j] = (unsigned short)r;
    }

    float c_reg = 0.0f;
    if (tid < DPW) c_reg = cstate[b * DH + (w << 5) + tid];
    __syncthreads();   // u_lds ready

    for (int tt = 0; tt < ct; ++tt) {
        const int s = t0 + tt + 1;     // computing h_s from h_{s-1}

        // px prefetch (independent of h): issue before the spin
        float pxv = 0.0f;
        if (tid < COLS)
            pxv = px[((size_t)tt * B_SZ + b) * FOUR_D + colg];

        // acquire h_{s-1}: threads 0..255 poll their own dim (tag==step)
        if (tid < DH) {
            if (s == 1) {
                h_lds[tid] = 0.0f;
            } else {
                const unsigned long long want = (unsigned long long)(unsigned)(s - 1);
                const unsigned long long* slot = hbuf +
                    (((size_t)((s - 1) & 1) * B_SZ + b) * DH + tid);
                unsigned long long v;
                do {
                    v = __hip_atomic_load(slot, __ATOMIC_RELAXED,
                                          __HIP_MEMORY_SCOPE_AGENT);
                } while ((v >> 32) != want);
                h_lds[tid] = __uint_as_float((unsigned)v);
            }
        }
        __syncthreads();   // B1: h_lds ready

        // GEMV from LDS-resident bf16 U: 8 chunks x (1 swizzled b128 read +
        // 2 broadcast h reads + 8 fp32 FMA). Logical chunk t lives at
        // physical chunk (t ^ cx) within this segment's 8-chunk window.
        float a0 = 0.f, a1 = 0.f;
#pragma unroll
        for (int t = 0; t < 8; ++t) {
            const uint4 q = *(const uint4*)
                &u_lds[c][(((seg << 3) + (t ^ cx)) << 3)];
            const int kk = kbase + (t << 3);
            const float4 h0 = *(const float4*)&h_lds[kk];
            const float4 h1 = *(const float4*)&h_lds[kk + 4];
            a0 += h0.x * bfu(q.x << 16) + h0.y * bfu(q.x & 0xffff0000u)
                + h0.z * bfu(q.y << 16) + h0.w * bfu(q.y & 0xffff0000u);
            a1 += h1.x * bfu(q.z << 16) + h1.y * bfu(q.z & 0xffff0000u)
                + h1.z * bfu(q.w << 16) + h1.w * bfu(q.w & 0xffff0000u);
        }
        red[seg][c] = a0 + a1;
        __syncthreads();   // B2: partials ready

        if (tid < COLS) {
            float pre = pxv + red[0][tid] + red[1][tid]
                            + red[2][tid] + red[3][tid];
            float a;
            if (tid < 96) {
                a = 1.0f / (1.0f + __expf(-pre));          // i, f, o
            } else {
                float e = __expf(-2.0f * pre);             // g = tanh
                a = 2.0f / (1.0f + e) - 1.0f;
            }
            act_s[tid] = a;
        }
        __syncthreads();   // B3: activations ready

        if (tid < DPW) {
            float ig = act_s[tid];
            float fg = act_s[32 + tid];
            float og = act_s[64 + tid];
            float gv = act_s[96 + tid];
            float cn = fg * c_reg + ig * gv;
            c_reg = cn;
            float ec = __expf(-2.0f * cn);
            float hn = og * (2.0f / (1.0f + ec) - 1.0f);
            const int d = (w << 5) + tid;
            // publish FIRST (critical path), out-store after
            unsigned long long pv =
                ((unsigned long long)(unsigned)s << 32) |
                (unsigned long long)__float_as_uint(hn);
            __hip_atomic_store(hbuf + (((size_t)(s & 1) * B_SZ + b) * DH + d),
                               pv, __ATOMIC_RELAXED, __HIP_MEMORY_SCOPE_AGENT);
            out[((size_t)b * T_SZ + (size_t)(s - 1)) * DH + d] = hn;
        }
        // no trailing barrier: next-iter h_lds writes are gated behind B3_tt
        // passage; red rewrite behind B1_{tt+1}; act_s behind B2_{tt+1}
        // (same argument as R4/R9).
    }

    if (tid < DPW) cstate[b * DH + (w << 5) + tid] = c_reg;
}

extern "C" void kernel_launch(void* const* d_in, const int* in_sizes, int n_in,
                              void* d_out, int out_size, void* d_ws, size_t ws_size,
                              hipStream_t stream) {
    const float* x    = (const float*)d_in[0];
    const float* W    = (const float*)d_in[1];
    const float* U    = (const float*)d_in[2];
    const float* bias = (const float*)d_in[3];
    float* out = (float*)d_out;

    // ws layout: cstate 32KB @0 | hbuf 128KB @32K | pxbuf @160K
    float* cstate = (float*)d_ws;
    unsigned long long* hbuf = (unsigned long long*)((char*)d_ws + 32 * 1024);
    size_t px_off = 160 * 1024;
    float* pxbuf = (float*)((char*)d_ws + px_off);

    size_t avail = (ws_size > px_off) ? (ws_size - px_off) : 0;
    size_t per_step = (size_t)B_SZ * FOUR_D * sizeof(float);  // 128 KB
    long ct_max = (long)(avail / per_step);
    int CT = (ct_max >= T_SZ) ? T_SZ : (int)ct_max;
    if (CT < 1) CT = 1;

    // zero cstate + hbuf each launch
    int zero_words = (160 * 1024) / 4;
    zero_ws<<<(zero_words + 255) / 256, 256, 0, stream>>>((unsigned int*)d_ws, zero_words);

    for (int t0 = 0; t0 < T_SZ; t0 += CT) {
        int ct = (T_SZ - t0 < CT) ? (T_SZ - t0) : CT;
        int rows = ct * B_SZ;
        px_gemm<<<rows / 16, 256, 0, stream>>>(x, W, bias, pxbuf, t0);
        lstm_scan11<<<B_SZ * NW, 512, 0, stream>>>(pxbuf, U, out, hbuf, cstate, t0, ct);
    }
}

// Round 14
// 4220.869 us; speedup vs baseline: 1.1131x; 1.1131x over previous
//
#include <hip/hip_runtime.h>
#include <math.h>

#define B_SZ 32
#define T_SZ 2048
#define DIN 256
#define DH 256
#define FOUR_D 1024

// scan decomposition: 8 WGs per batch, 512 threads each (R9-proven skeleton)
#define NW 8
#define DPW 32
#define COLS 128       // preact cols per WG (4 gates x 32 dims)
#define KSEG 4         // 512 threads = 128 cols x 4 K-segments
#define KLEN 64        // K elements per segment -> 8 f16 chunks of 8

typedef _Float16 f16x8 __attribute__((ext_vector_type(8)));
typedef _Float16 f16x2 __attribute__((ext_vector_type(2)));

#if __has_builtin(__builtin_amdgcn_fdot2)
#define FDOT2(a, b, c) __builtin_amdgcn_fdot2((a), (b), (c), false)
#else
__device__ __forceinline__ float fdot2_emu(f16x2 a, f16x2 b, float c) {
    return c + (float)a[0] * (float)b[0] + (float)a[1] * (float)b[1];
}
#define FDOT2(a, b, c) fdot2_emu((a), (b), (c))
#endif

__global__ void zero_ws(unsigned int* p, int n) {
    int i = blockIdx.x * blockDim.x + threadIdx.x;
    if (i < n) p[i] = 0u;
}

// px[r][f] = bias[f] + sum_k x_row(r)[k] * W[k][f];  r = tt*32 + b   (proven)
__global__ __launch_bounds__(256) void px_gemm(
    const float* __restrict__ x, const float* __restrict__ W,
    const float* __restrict__ bias, float* __restrict__ px,
    int t0)
{
    __shared__ float xt[16][DIN];
    const int tid = threadIdx.x;
    const int rbase = blockIdx.x * 16;

    {
        int row = tid >> 4;
        int seg = (tid & 15) * 16;
        int r = rbase + row;
        int bb = r & 31;
        int tt = r >> 5;
        const float4* s4 = (const float4*)(x + ((size_t)bb * T_SZ + (size_t)(t0 + tt)) * DIN + seg);
        float4* dst = (float4*)&xt[row][seg];
        dst[0] = s4[0]; dst[1] = s4[1]; dst[2] = s4[2]; dst[3] = s4[3];
    }
    __syncthreads();

    const int j = tid * 4;
    float4 bv = *(const float4*)&bias[j];
    float acc[16][4];
#pragma unroll
    for (int r = 0; r < 16; ++r) {
        acc[r][0] = bv.x; acc[r][1] = bv.y; acc[r][2] = bv.z; acc[r][3] = bv.w;
    }

    for (int k = 0; k < DIN; k += 4) {
        float4 w0 = *(const float4*)&W[(size_t)(k + 0) * FOUR_D + j];
        float4 w1 = *(const float4*)&W[(size_t)(k + 1) * FOUR_D + j];
        float4 w2 = *(const float4*)&W[(size_t)(k + 2) * FOUR_D + j];
        float4 w3 = *(const float4*)&W[(size_t)(k + 3) * FOUR_D + j];
#pragma unroll
        for (int r = 0; r < 16; ++r) {
            float4 xv = *(const float4*)&xt[r][k];
            acc[r][0] += xv.x * w0.x + xv.y * w1.x + xv.z * w2.x + xv.w * w3.x;
            acc[r][1] += xv.x * w0.y + xv.y * w1.y + xv.z * w2.y + xv.w * w3.y;
            acc[r][2] += xv.x * w0.z + xv.y * w1.z + xv.z * w2.z + xv.w * w3.z;
            acc[r][3] += xv.x * w0.w + xv.y * w1.w + xv.z * w2.w + xv.w * w3.w;
        }
    }

#pragma unroll
    for (int r = 0; r < 16; ++r) {
        float4 st = make_float4(acc[r][0], acc[r][1], acc[r][2], acc[r][3]);
        *(float4*)&px[((size_t)(rbase + r)) * FOUR_D + j] = st;
    }
}

// Transposed scan (R9 skeleton), U-slice resident in LDS as f16 (64 KB,
// staged once), consumed via v_dot2_f32_f16 (packed MAC, no unpack VALU —
// R13's regression term). h is converted to f16 by the pollers; publish and
// output stay fp32. Chunk layout XOR-swizzled by (c&7) as in R13.
__global__ __launch_bounds__(512, 2) void lstm_scan12(
    const float* __restrict__ px, const float* __restrict__ U,
    float* __restrict__ out, unsigned long long* __restrict__ hbuf,
    float* __restrict__ cstate, int t0, int ct)
{
    __shared__ _Float16 u_lds[COLS][256];   // 64 KB f16 U-slice
    __shared__ _Float16 h1_lds[DH];         // f16 h (poller-converted)
    __shared__ float red[KSEG][COLS + 1];
    __shared__ float act_s[COLS];

    const int b = blockIdx.x >> 3;     // batch (batch-contiguous)
    const int w = blockIdx.x & 7;      // WG-within-batch
    const int tid = threadIdx.x;
    const int c = tid & (COLS - 1);    // col within WG: 0..127
    const int seg = tid >> 7;          // 0..3
    const int kbase = seg << 6;        // 0,64,128,192
    const int cx = c & 7;              // swizzle key
    const int gg = c >> 5, jj = c & 31;
    const int colg = (gg << 8) + (w << 5) + jj;   // global preact column

    // ---- prologue: stage U-slice to LDS as f16 (RNE cast), chunk-swizzled
#pragma unroll 4
    for (int it = 0; it < 64; ++it) {
        int lin = (it << 9) + tid;
        int k = lin >> 7;               // 0..255
        int cidx = lin & 127;
        int gcol = ((cidx >> 5) << 8) + (w << 5) + (cidx & 31);
        float v = U[(size_t)k * FOUR_D + gcol];
        int m = k >> 3, j = k & 7;      // logical chunk 0..31, elem
        int phys = (m & 24) | ((m & 7) ^ (cidx & 7));
        u_lds[cidx][(phys << 3) + j] = (_Float16)v;
    }

    float c_reg = 0.0f;
    if (tid < DPW) c_reg = cstate[b * DH + (w << 5) + tid];
    __syncthreads();   // u_lds ready

    for (int tt = 0; tt < ct; ++tt) {
        const int s = t0 + tt + 1;     // computing h_s from h_{s-1}

        // px prefetch (independent of h): issue before the spin
        float pxv = 0.0f;
        if (tid < COLS)
            pxv = px[((size_t)tt * B_SZ + b) * FOUR_D + colg];

        // acquire h_{s-1}: threads 0..255 poll their own dim (tag==step),
        // convert to f16 into h1_lds
        if (tid < DH) {
            if (s == 1) {
                h1_lds[tid] = (_Float16)0.0f;
            } else {
                const unsigned long long want = (unsigned long long)(unsigned)(s - 1);
                const unsigned long long* slot = hbuf +
                    (((size_t)((s - 1) & 1) * B_SZ + b) * DH + tid);
                unsigned long long v;
                do {
                    v = __hip_atomic_load(slot, __ATOMIC_RELAXED,
                                          __HIP_MEMORY_SCOPE_AGENT);
                } while ((v >> 32) != want);
                h1_lds[tid] = (_Float16)__uint_as_float((unsigned)v);
            }
        }
        __syncthreads();   // B1: h1_lds ready

        // GEMV: 8 chunks x { 1 swizzled b128 U read + 1 b128 h read (wave-
        // uniform, broadcast) + 4 fdot2 }. 4 accumulators break the chain.
        float a0 = 0.f, a1 = 0.f, a2 = 0.f, a3 = 0.f;
#pragma unroll
        for (int t = 0; t < 8; ++t) {
            const f16x2* q = (const f16x2*)&u_lds[c][((seg << 3) + (t ^ cx)) << 3];
            const f16x2* hp = (const f16x2*)&h1_lds[kbase + (t << 3)];
            a0 = FDOT2(q[0], hp[0], a0);
            a1 = FDOT2(q[1], hp[1], a1);
            a2 = FDOT2(q[2], hp[2], a2);
            a3 = FDOT2(q[3], hp[3], a3);
        }
        red[seg][c] = (a0 + a1) + (a2 + a3);
        __syncthreads();   // B2: partials ready

        if (tid < COLS) {
            float pre = pxv + red[0][tid] + red[1][tid]
                            + red[2][tid] + red[3][tid];
            float a;
            if (tid < 96) {
                a = 1.0f / (1.0f + __expf(-pre));          // i, f, o
            } else {
                float e = __expf(-2.0f * pre);             // g = tanh
                a = 2.0f / (1.0f + e) - 1.0f;
            }
            act_s[tid] = a;
        }
        __syncthreads();   // B3: activations ready

        if (tid < DPW) {
            float ig = act_s[tid];
            float fg = act_s[32 + tid];
            float og = act_s[64 + tid];
            float gv = act_s[96 + tid];
            float cn = fg * c_reg + ig * gv;
            c_reg = cn;
            float ec = __expf(-2.0f * cn);
            float hn = og * (2.0f / (1.0f + ec) - 1.0f);
            const int d = (w << 5) + tid;
            // publish FIRST (critical path), out-store after; both fp32
            unsigned long long pv =
                ((unsigned long long)(unsigned)s << 32) |
                (unsigned long long)__float_as_uint(hn);
            __hip_atomic_store(hbuf + (((size_t)(s & 1) * B_SZ + b) * DH + d),
                               pv, __ATOMIC_RELAXED, __HIP_MEMORY_SCOPE_AGENT);
            out[((size_t)b * T_SZ + (size_t)(s - 1)) * DH + d] = hn;
        }
        // no trailing barrier: h1_lds rewrite (pollers, pre-B1 of t+1) occurs
        // after B3_t, and all h1_lds readers finished before B2_t; red rewrite
        // gated behind B1_{t+1}; act_s behind B2_{t+1}. (R9 argument.)
    }

    if (tid < DPW) cstate[b * DH + (w << 5) + tid] = c_reg;
}

extern "C" void kernel_launch(void* const* d_in, const int* in_sizes, int n_in,
                              void* d_out, int out_size, void* d_ws, size_t ws_size,
                              hipStream_t stream) {
    const float* x    = (const float*)d_in[0];
    const float* W    = (const float*)d_in[1];
    const float* U    = (const float*)d_in[2];
    const float* bias = (const float*)d_in[3];
    float* out = (float*)d_out;

    // ws layout: cstate 32KB @0 | hbuf 128KB @32K | pxbuf @160K
    float* cstate = (float*)d_ws;
    unsigned long long* hbuf = (unsigned long long*)((char*)d_ws + 32 * 1024);
    size_t px_off = 160 * 1024;
    float* pxbuf = (float*)((char*)d_ws + px_off);

    size_t avail = (ws_size > px_off) ? (ws_size - px_off) : 0;
    size_t per_step = (size_t)B_SZ * FOUR_D * sizeof(float);  // 128 KB
    long ct_max = (long)(avail / per_step);
    int CT = (ct_max >= T_SZ) ? T_SZ : (int)ct_max;
    if (CT < 1) CT = 1;

    // zero cstate + hbuf each launch
    int zero_words = (160 * 1024) / 4;
    zero_ws<<<(zero_words + 255) / 256, 256, 0, stream>>>((unsigned int*)d_ws, zero_words);

    for (int t0 = 0; t0 < T_SZ; t0 += CT) {
        int ct = (T_SZ - t0 < CT) ? (T_SZ - t0) : CT;
        int rows = ct * B_SZ;
        px_gemm<<<rows / 16, 256, 0, stream>>>(x, W, bias, pxbuf, t0);
        lstm_scan12<<<B_SZ * NW, 512, 0, stream>>>(pxbuf, U, out, hbuf, cstate, t0, ct);
    }
}